// Round 14
// baseline (260.022 us; speedup 1.0000x reference)
//
#include <hip/hip_runtime.h>
#include <hip/hip_bf16.h>

#define N_NODES   51200
#define N_GRAPHS  64
#define N_EDGES   819200
#define DIM_IN    128
#define DH        64
#define HEADS     3
#define DIM_OUT   64
#define CAP       96   // bucket capacity per dst node; P(deg>96 | Poisson(16)) ~ 1e-40
#define NPART     8    // XCD-partition count for scatter
#define PART_SZ   (N_NODES / NPART)
#define NSCAT     (NPART * (N_EDGES / 2048))

typedef __hip_bfloat16 bf16;
typedef short bf16x8 __attribute__((ext_vector_type(8)));
typedef float f32x4  __attribute__((ext_vector_type(4)));
typedef float f32x2  __attribute__((ext_vector_type(2)));

__device__ __forceinline__ float b2f(bf16 x) { return __bfloat162float(x); }
__device__ __forceinline__ bf16  f2b(float x) { return __float2bfloat16(x); }
__device__ __forceinline__ short f2bs(float x) { return (short)__bfloat16_as_ushort(f2b(x)); }
__device__ __forceinline__ float leaky(float x, float s) { return x >= 0.f ? x : s * x; }
// flag-branched input load: f32==1 -> data is float32 (ACTIVE path per R10-R12 bisect)
__device__ __forceinline__ float ldin(const void* p, size_t i, int f32) {
    return f32 ? ((const float*)p)[i] : b2f(((const bf16*)p)[i]);
}
__device__ __forceinline__ bf16x8 ld8(const void* p, size_t i, int f32) {
    if (!f32) return *((const bf16x8*)((const short*)p + i));
    const float* f = (const float*)p + i;
    bf16x8 r;
    #pragma unroll
    for (int j = 0; j < 8; ++j) r[j] = f2bs(f[j]);
    return r;
}

// ---------- fused scatter (XCD-partitioned buckets) + weight prep (self-detecting dtype)
__global__ __launch_bounds__(256) void scatter_prep_kernel(const int* __restrict__ src,
                                                           const int* __restrict__ dst,
                                                           int* __restrict__ cursor,
                                                           unsigned short* __restrict__ bucket,
                                                           const unsigned short* __restrict__ Xu,
                                                           const void* __restrict__ W1,
                                                           const void* __restrict__ Wsrc,
                                                           const void* __restrict__ Wdst,
                                                           const void* __restrict__ Wf,
                                                           const void* __restrict__ att_src,
                                                           const void* __restrict__ att_dst,
                                                           int* __restrict__ flag,
                                                           short* __restrict__ W1t,
                                                           short* __restrict__ Wallt,
                                                           short* __restrict__ Wft,
                                                           short* __restrict__ Wat) {
    if (blockIdx.x < NSCAT) {
        const int p = blockIdx.x & (NPART - 1);
        const int slice = blockIdx.x >> 3;
        const int lo = p * PART_SZ, hi = lo + PART_SZ;
        const int base = slice * 2048 + threadIdx.x;
        #pragma unroll
        for (int t = 0; t < 8; ++t) {
            int e = base + t * 256;
            int d = dst[e];
            if (d >= lo && d < hi) {
                int pos = atomicAdd(&cursor[d], 1);
                if (pos < CAP) bucket[(size_t)d * CAP + pos] = (unsigned short)src[e];
            }
        }
        return;
    }
    // ---- prep blocks: self-detect dtype (identical decision rule to the old detect_kernel)
    __shared__ int cnt;
    int tid = threadIdx.x;
    if (tid == 0) cnt = 0;
    __syncthreads();
    int local = 0;
    for (int i = tid * 2; i < 8192; i += 512) {
        unsigned e = (Xu[i] >> 7) & 0xFF;
        if (e >= 110 && e <= 135) local++;
    }
    atomicAdd(&cnt, local);
    __syncthreads();
    const int f32 = (cnt < 2048) ? 1 : 0;   // 1 = fp32, 0 = bf16
    if (blockIdx.x == NSCAT && tid == 0) *flag = f32;  // publish for downstream kernels

    int idx = (blockIdx.x - NSCAT) * 256 + tid;
    if (idx < 8192) {
        int n = idx >> 7, k = idx & 127;
        W1t[idx] = f2bs(ldin(W1, (size_t)k * 64 + n, f32));
    } else if (idx < 8192 + 12288) {
        int j = idx - 8192;
        int n = j >> 6, k = j & 63;
        Wallt[j] = f2bs(ldin(Wsrc, (size_t)k * 192 + n, f32));
    } else if (idx < 8192 + 12288 + 8192) {
        int j = idx - 20480;
        int n = j >> 7, k = j & 127;
        Wft[j] = f2bs(ldin(Wf, (size_t)k * 64 + n, f32));
    } else if (idx < 8192 + 12288 + 8192 + 1024) {
        int j = idx - 28672;
        int n = j >> 6, k = j & 63;
        float v = 0.f;
        if (n < 3) {
            for (int c = 0; c < 64; ++c)
                v += ldin(Wsrc, (size_t)k * 192 + n * 64 + c, f32) * ldin(att_src, n * 64 + c, f32);
        } else if (n < 6) {
            for (int c = 0; c < 64; ++c)
                v += ldin(Wdst, (size_t)k * 192 + (n - 3) * 64 + c, f32) * ldin(att_dst, (n - 3) * 64 + c, f32);
        }
        Wat[j] = f2bs(v);
    }
}

// ---------- K1: one wave per 16 rows, barrier-free; x_src stored as 3 fp8 byte-planes
__global__ __launch_bounds__(64) void k1_kernel(const void* __restrict__ X,
                                                const short* __restrict__ W1t,
                                                const short* __restrict__ Wallt,
                                                const short* __restrict__ Wat,
                                                const void* __restrict__ b1,
                                                const int* __restrict__ flagp,
                                                bf16* __restrict__ h_bf,
                                                unsigned char* __restrict__ xa,
                                                unsigned char* __restrict__ xb,
                                                unsigned char* __restrict__ xc,
                                                float* __restrict__ a_src4,
                                                float* __restrict__ a_dst4) {
    const int f32 = *flagp;
    __shared__ short hs[16 * 72];            // 16-row strip, stride 72 (2-way max: free)
    const int lane = threadIdx.x & 63;
    const int lm   = lane & 15;
    const int q    = lane >> 4;
    const int row0 = blockIdx.x * 16;

    #pragma unroll
    for (int ct = 0; ct < 4; ++ct) {
        f32x4 acc = {0.f, 0.f, 0.f, 0.f};
        #pragma unroll
        for (int kc = 0; kc < 4; ++kc) {
            bf16x8 a = ld8(X, (size_t)(row0 + lm) * 128 + kc * 32 + q * 8, f32);
            bf16x8 b = *((const bf16x8*)(W1t + (size_t)(ct * 16 + lm) * 128 + kc * 32 + q * 8));
            acc = __builtin_amdgcn_mfma_f32_16x16x32_bf16(a, b, acc, 0, 0, 0);
        }
        const float bias = ldin(b1, ct * 16 + lm, f32);
        #pragma unroll
        for (int r = 0; r < 4; ++r) {
            int rl = q * 4 + r;
            float v = leaky(acc[r] + bias, 0.01f);
            short hv = f2bs(v);
            hs[rl * 72 + ct * 16 + lm] = hv;
            h_bf[(size_t)(row0 + rl) * 64 + ct * 16 + lm] = __ushort_as_bfloat16((unsigned short)hv);
        }
    }
    asm volatile("s_waitcnt lgkmcnt(0)" ::: "memory");   // wave-local LDS fence (no barrier)

    bf16x8 a0 = *((const bf16x8*)(hs + lm * 72 + q * 8));
    bf16x8 a1 = *((const bf16x8*)(hs + lm * 72 + 32 + q * 8));
    #pragma unroll
    for (int t = 0; t < 4; ++t) {
        f32x4 acc[3];
        #pragma unroll
        for (int hh = 0; hh < 3; ++hh) {
            acc[hh] = (f32x4){0.f, 0.f, 0.f, 0.f};
            bf16x8 b0 = *((const bf16x8*)(Wallt + (size_t)(hh * 64 + t * 16 + lm) * 64 + q * 8));
            bf16x8 b1v = *((const bf16x8*)(Wallt + (size_t)(hh * 64 + t * 16 + lm) * 64 + 32 + q * 8));
            acc[hh] = __builtin_amdgcn_mfma_f32_16x16x32_bf16(a0, b0, acc[hh], 0, 0, 0);
            acc[hh] = __builtin_amdgcn_mfma_f32_16x16x32_bf16(a1, b1v, acc[hh], 0, 0, 0);
        }
        #pragma unroll
        for (int r = 0; r < 4; ++r) {
            size_t o = (size_t)(row0 + q * 4 + r) * 64 + t * 16 + lm;
            unsigned p01 = (unsigned)__builtin_amdgcn_cvt_pk_fp8_f32(acc[0][r], acc[1][r], 0, false);
            unsigned p2  = (unsigned)__builtin_amdgcn_cvt_pk_fp8_f32(acc[2][r], 0.f, 0, false);
            xa[o] = (unsigned char)(p01 & 0xFFu);
            xb[o] = (unsigned char)((p01 >> 8) & 0xFFu);
            xc[o] = (unsigned char)(p2 & 0xFFu);
        }
    }
    f32x4 acca = {0.f, 0.f, 0.f, 0.f};
    bf16x8 b0 = *((const bf16x8*)(Wat + (size_t)lm * 64 + q * 8));
    bf16x8 b1v = *((const bf16x8*)(Wat + (size_t)lm * 64 + 32 + q * 8));
    acca = __builtin_amdgcn_mfma_f32_16x16x32_bf16(a0, b0, acca, 0, 0, 0);
    acca = __builtin_amdgcn_mfma_f32_16x16x32_bf16(a1, b1v, acca, 0, 0, 0);
    if (lm < 6) {
        #pragma unroll
        for (int r = 0; r < 4; ++r) {
            int row = row0 + q * 4 + r;
            if (lm < 3) a_src4[(size_t)row * 4 + lm] = acca[r];
            else        a_dst4[(size_t)row * 4 + (lm - 3)] = acca[r];
        }
    }
}

// ---------- edge aggregation: wave per dst node; 3-plane fp8 gather (3x64B lines/row vs 4)
__global__ __launch_bounds__(256) void edge_kernel(const unsigned short* __restrict__ bucket,
                                                   const int* __restrict__ cursor,
                                                   const float* __restrict__ a_src4,
                                                   const float* __restrict__ a_dst4,
                                                   const unsigned char* __restrict__ xa,
                                                   const unsigned char* __restrict__ xb,
                                                   const unsigned char* __restrict__ xc,
                                                   const void* __restrict__ gat_bias,
                                                   const int* __restrict__ flagp,
                                                   float4* __restrict__ dstinfo,
                                                   bf16* __restrict__ out_agg) {
    const int f32 = *flagp;
    const int lane = threadIdx.x & 63;
    const int w = threadIdx.x >> 6;
    const int n = blockIdx.x * 4 + w;
    const int dg = min(cursor[n], CAP);
    const float4 ad = ((const float4*)a_dst4)[n];
    __shared__ float4 buf[4][64];
    float den0 = 0.f, den1 = 0.f, den2 = 0.f;
    float acc0 = 0.f, acc1 = 0.f, acc2 = 0.f;
    for (int c0 = 0; c0 < dg; c0 += 64) {
        int cnt = min(64, dg - c0);
        if (lane < cnt) {
            int s = bucket[(size_t)n * CAP + c0 + lane];
            const float4 as = ((const float4*)a_src4)[s];
            float e0 = __expf(leaky(as.x + ad.x, 0.2f));
            float e1 = __expf(leaky(as.y + ad.y, 0.2f));
            float e2 = __expf(leaky(as.z + ad.z, 0.2f));
            buf[w][lane] = make_float4(e0, e1, e2, __int_as_float(s));
        }
        asm volatile("s_waitcnt lgkmcnt(0)" ::: "memory");
        int j = 0;
        for (; j + 8 <= cnt; j += 8) {
            float4 r[8]; int b0[8], b1[8], b2[8];
            #pragma unroll
            for (int u = 0; u < 8; ++u) r[u] = buf[w][j + u];
            #pragma unroll
            for (int u = 0; u < 8; ++u) {
                size_t o = (size_t)__float_as_int(r[u].w) * 64 + lane;
                b0[u] = xa[o]; b1[u] = xb[o]; b2[u] = xc[o];
            }
            #pragma unroll
            for (int u = 0; u < 8; ++u) {
                acc0 += r[u].x * __builtin_amdgcn_cvt_f32_fp8(b0[u], 0);
                acc1 += r[u].y * __builtin_amdgcn_cvt_f32_fp8(b1[u], 0);
                acc2 += r[u].z * __builtin_amdgcn_cvt_f32_fp8(b2[u], 0);
                den0 += r[u].x; den1 += r[u].y; den2 += r[u].z;
            }
        }
        for (; j < cnt; ++j) {
            float4 r = buf[w][j];
            size_t o = (size_t)__float_as_int(r.w) * 64 + lane;
            acc0 += r.x * __builtin_amdgcn_cvt_f32_fp8((int)xa[o], 0);
            acc1 += r.y * __builtin_amdgcn_cvt_f32_fp8((int)xb[o], 0);
            acc2 += r.z * __builtin_amdgcn_cvt_f32_fp8((int)xc[o], 0);
            den0 += r.x; den1 += r.y; den2 += r.z;
        }
    }
    float inv0 = den0 > 0.f ? 1.f / den0 : 0.f;
    float inv1 = den1 > 0.f ? 1.f / den1 : 0.f;
    float inv2 = den2 > 0.f ? 1.f / den2 : 0.f;
    float outv = (acc0 * inv0 + acc1 * inv1 + acc2 * inv2) * (1.f / 3.f) + ldin(gat_bias, lane, f32);
    out_agg[(size_t)n * DH + lane] = f2b(outv);
    if (lane == 0) {
        dstinfo[(size_t)n * 2 + 0] = make_float4(ad.x, ad.y, ad.z, 0.f);
        dstinfo[(size_t)n * 2 + 1] = make_float4(inv0, inv1, inv2, 0.f);
    }
}

// ---------- fused attn (edge-order, blocks 0..3199) + g3 MFMA (blocks 3200..3999)
__global__ __launch_bounds__(256) void attn_g3_kernel(const int* __restrict__ src,
                                                      const int* __restrict__ dst,
                                                      const float* __restrict__ a_src4,
                                                      const float4* __restrict__ dstinfo,
                                                      const bf16* __restrict__ h_bf,
                                                      const bf16* __restrict__ out_agg,
                                                      const short* __restrict__ Wft,
                                                      const void* __restrict__ bfv,
                                                      const int* __restrict__ flagp,
                                                      bf16* __restrict__ y_bf,
                                                      void* __restrict__ d_out) {
    const int f32 = *flagp;
    __shared__ short cs[64 * 136];           // used by g3 branch only
    if (blockIdx.x < N_EDGES / 256) {
        int e = blockIdx.x * 256 + threadIdx.x;
        int s = src[e], d = dst[e];
        const float4 as = ((const float4*)a_src4)[s];
        const float4 ad = dstinfo[(size_t)d * 2 + 0];
        const float4 cv = dstinfo[(size_t)d * 2 + 1];
        float a0 = __expf(leaky(as.x + ad.x, 0.2f)) * cv.x;
        float a1 = __expf(leaky(as.y + ad.y, 0.2f)) * cv.y;
        float a2 = __expf(leaky(as.z + ad.z, 0.2f)) * cv.z;
        size_t o = (size_t)N_GRAPHS * DIM_OUT + (size_t)e * 3;
        if (f32) {
            float* p = (float*)d_out;
            p[o] = a0; p[o + 1] = a1; p[o + 2] = a2;
        } else {
            bf16* p = (bf16*)d_out;
            p[o] = f2b(a0); p[o + 1] = f2b(a1); p[o + 2] = f2b(a2);
        }
        return;
    }
    const int bid  = blockIdx.x - N_EDGES / 256;
    const int tid  = threadIdx.x;
    const int w    = tid >> 6;
    const int lane = tid & 63;
    const int lm   = lane & 15;
    const int q    = lane >> 4;
    const int row0 = bid * 64;
    for (int idx = tid; idx < 64 * 64; idx += 256) {
        int r = idx >> 6, k = idx & 63;
        cs[r * 136 + k] = f2bs(leaky(b2f(h_bf[(size_t)(row0 + r) * 64 + k]), 0.01f));
    }
    for (int idx = tid; idx < 64 * 64; idx += 256) {
        int r = idx >> 6, k = idx & 63;
        cs[r * 136 + 64 + k] = f2bs(leaky(b2f(out_agg[(size_t)(row0 + r) * 64 + k]), 0.01f));
    }
    __syncthreads();
    const float bias = ldin(bfv, w * 16 + lm, f32);
    for (int mt = 0; mt < 4; ++mt) {
        f32x4 acc = {0.f, 0.f, 0.f, 0.f};
        #pragma unroll
        for (int kc = 0; kc < 4; ++kc) {
            bf16x8 a = *((const bf16x8*)(cs + (mt * 16 + lm) * 136 + kc * 32 + q * 8));
            bf16x8 b = *((const bf16x8*)(Wft + (size_t)(w * 16 + lm) * 128 + kc * 32 + q * 8));
            acc = __builtin_amdgcn_mfma_f32_16x16x32_bf16(a, b, acc, 0, 0, 0);
        }
        #pragma unroll
        for (int r = 0; r < 4; ++r) {
            int row = row0 + mt * 16 + q * 4 + r;
            y_bf[(size_t)row * 64 + w * 16 + lm] = f2b(acc[r] + bias);
        }
    }
}

// ---------- graph mean-pool: 1024 threads per graph
__global__ __launch_bounds__(1024) void pool_kernel(const bf16* __restrict__ y_bf,
                                                    const int* __restrict__ ptr,
                                                    const int* __restrict__ flagp,
                                                    void* __restrict__ d_out) {
    __shared__ float part[16][64];
    const int f32 = *flagp;
    const int g = blockIdx.x;
    const int w = threadIdx.x >> 6, lane = threadIdx.x & 63;
    const int lo = ptr[g], hi = ptr[g + 1];
    const int cnt = hi - lo;
    float s = 0.f;
    for (int i = lo + w; i < hi; i += 16) s += b2f(y_bf[(size_t)i * DIM_OUT + lane]);
    part[w][lane] = s;
    __syncthreads();
    if (threadIdx.x < 64) {
        float t = 0.f;
        #pragma unroll
        for (int k = 0; k < 16; ++k) t += part[k][threadIdx.x];
        float v = t / (float)cnt;
        if (f32) ((float*)d_out)[g * DIM_OUT + threadIdx.x] = v;
        else     ((bf16*)d_out)[g * DIM_OUT + threadIdx.x]  = f2b(v);
    }
}

extern "C" void kernel_launch(void* const* d_in, const int* in_sizes, int n_in,
                              void* d_out, int out_size, void* d_ws, size_t ws_size,
                              hipStream_t stream) {
    const void* X        = d_in[0];
    const void* W1       = d_in[1];
    const void* b1       = d_in[2];
    const void* Wsrc     = d_in[3];
    const void* Wdst     = d_in[4];
    const void* att_src  = d_in[5];
    const void* att_dst  = d_in[6];
    const void* gat_bias = d_in[7];
    const void* Wf       = d_in[8];
    const void* bfv      = d_in[9];
    const int*  ei       = (const int*)d_in[10];
    const int*  ptr      = (const int*)d_in[11];
    const int*  src  = ei;
    const int*  dstp = ei + N_EDGES;

    char* ws = (char*)d_ws;
    size_t off_b = 0;
    auto alloc = [&](size_t bytes) -> char* {
        char* p = ws + off_b;
        off_b += (bytes + 255) & ~(size_t)255;
        return p;
    };
    int*     flag    = (int*)    alloc(256);
    short*   W1t     = (short*)  alloc(8192 * 2);
    short*   Wallt   = (short*)  alloc(12288 * 2);
    short*   Wft     = (short*)  alloc(8192 * 2);
    short*   Wat     = (short*)  alloc(1024 * 2);
    bf16*    h_bf    = (bf16*)   alloc((size_t)N_NODES * 64 * 2);
    unsigned char* xa = (unsigned char*)alloc((size_t)N_NODES * 64);  // fp8 plane head0
    unsigned char* xb = (unsigned char*)alloc((size_t)N_NODES * 64);  // head1
    unsigned char* xc = (unsigned char*)alloc((size_t)N_NODES * 64);  // head2
    float*   a_src4  = (float*)  alloc((size_t)N_NODES * 16);
    float*   a_dst4  = (float*)  alloc((size_t)N_NODES * 16);
    float4*  dstinfo = (float4*) alloc((size_t)N_NODES * 2 * 16);
    bf16*    out_agg = (bf16*)   alloc((size_t)N_NODES * 64 * 2);
    int*     cursor  = (int*)    alloc((size_t)N_NODES * 4);
    unsigned short* bucket = (unsigned short*)alloc((size_t)N_NODES * CAP * 2);
    bf16*    y_bf    = (bf16*)   xa;           // alias: planes dead before g3; y spans xa+xb
    if (off_b > ws_size) return;

    hipMemsetAsync(cursor, 0, (size_t)N_NODES * 4, stream);
    hipLaunchKernelGGL(scatter_prep_kernel, dim3(NSCAT + 116), dim3(256), 0, stream,
                       src, dstp, cursor, bucket, (const unsigned short*)X,
                       W1, Wsrc, Wdst, Wf, att_src, att_dst, flag, W1t, Wallt, Wft, Wat);
    hipLaunchKernelGGL(k1_kernel, dim3(N_NODES / 16), dim3(64), 0, stream,
                       X, W1t, Wallt, Wat, b1, flag, h_bf, xa, xb, xc, a_src4, a_dst4);
    hipLaunchKernelGGL(edge_kernel, dim3(N_NODES / 4), dim3(256), 0, stream,
                       bucket, cursor, a_src4, a_dst4, xa, xb, xc, gat_bias, flag,
                       dstinfo, out_agg);
    hipLaunchKernelGGL(attn_g3_kernel, dim3(N_EDGES / 256 + N_NODES / 64), dim3(256), 0, stream,
                       src, dstp, a_src4, dstinfo, h_bf, out_agg, Wft, bfv, flag, y_bf, d_out);
    hipLaunchKernelGGL(pool_kernel, dim3(N_GRAPHS), dim3(1024), 0, stream, y_bf, ptr, flag, d_out);
}

// Round 15
// 240.172 us; speedup vs baseline: 1.0827x; 1.0827x over previous
//
#include <hip/hip_runtime.h>
#include <hip/hip_bf16.h>

#define N_NODES   51200
#define N_GRAPHS  64
#define N_EDGES   819200
#define DIM_IN    128
#define DH        64
#define HEADS     3
#define DIM_OUT   64
#define CAP       96   // bucket capacity per dst node; P(deg>96 | Poisson(16)) ~ 1e-40
#define NPART     8    // XCD-partition count for scatter
#define PART_SZ   (N_NODES / NPART)

typedef __hip_bfloat16 bf16;
typedef short bf16x8 __attribute__((ext_vector_type(8)));
typedef float f32x4  __attribute__((ext_vector_type(4)));
typedef float f32x2  __attribute__((ext_vector_type(2)));

__device__ __forceinline__ float b2f(bf16 x) { return __bfloat162float(x); }
__device__ __forceinline__ bf16  f2b(float x) { return __float2bfloat16(x); }
__device__ __forceinline__ short f2bs(float x) { return (short)__bfloat16_as_ushort(f2b(x)); }
__device__ __forceinline__ float leaky(float x, float s) { return x >= 0.f ? x : s * x; }
// flag-branched input load: f32==1 -> data is float32 (the ACTIVE path per R10/R11/R12 bisect)
__device__ __forceinline__ float ldin(const void* p, size_t i, int f32) {
    return f32 ? ((const float*)p)[i] : b2f(((const bf16*)p)[i]);
}
__device__ __forceinline__ bf16x8 ld8(const void* p, size_t i, int f32) {
    if (!f32) return *((const bf16x8*)((const short*)p + i));
    const float* f = (const float*)p + i;
    bf16x8 r;
    #pragma unroll
    for (int j = 0; j < 8; ++j) r[j] = f2bs(f[j]);
    return r;
}

// ---------- dtype detector (LOAD-BEARING: inputs are fp32; this must stay)
__global__ __launch_bounds__(256) void detect_kernel(const unsigned short* __restrict__ Xu,
                                                     int* __restrict__ flag) {
    __shared__ int cnt;
    int tid = threadIdx.x;
    if (tid == 0) cnt = 0;
    __syncthreads();
    int local = 0;
    for (int i = tid * 2; i < 8192; i += 512) {
        unsigned e = (Xu[i] >> 7) & 0xFF;
        if (e >= 110 && e <= 135) local++;
    }
    atomicAdd(&cnt, local);
    __syncthreads();
    if (tid == 0) *flag = (cnt < 2048) ? 1 : 0;  // 1 = fp32, 0 = bf16
}

// ---------- fused scatter (XCD-partitioned buckets) + weight-transpose prep
__global__ __launch_bounds__(256) void scatter_prep_kernel(const int* __restrict__ src,
                                                           const int* __restrict__ dst,
                                                           int* __restrict__ cursor,
                                                           unsigned short* __restrict__ bucket,
                                                           const void* __restrict__ W1,
                                                           const void* __restrict__ Wsrc,
                                                           const void* __restrict__ Wdst,
                                                           const void* __restrict__ Wf,
                                                           const void* __restrict__ att_src,
                                                           const void* __restrict__ att_dst,
                                                           const int* __restrict__ flagp,
                                                           short* __restrict__ W1t,
                                                           short* __restrict__ Wallt,
                                                           short* __restrict__ Wft,
                                                           short* __restrict__ Wat) {
    if (blockIdx.x < NPART * (N_EDGES / 2048)) {
        const int p = blockIdx.x & (NPART - 1);
        const int slice = blockIdx.x >> 3;
        const int lo = p * PART_SZ, hi = lo + PART_SZ;
        const int base = slice * 2048 + threadIdx.x;
        #pragma unroll
        for (int t = 0; t < 8; ++t) {
            int e = base + t * 256;
            int d = dst[e];
            if (d >= lo && d < hi) {
                int pos = atomicAdd(&cursor[d], 1);
                if (pos < CAP) bucket[(size_t)d * CAP + pos] = (unsigned short)src[e];
            }
        }
        return;
    }
    const int f32 = *flagp;
    int idx = (blockIdx.x - NPART * (N_EDGES / 2048)) * 256 + threadIdx.x;
    if (idx < 8192) {
        int n = idx >> 7, k = idx & 127;
        W1t[idx] = f2bs(ldin(W1, (size_t)k * 64 + n, f32));
    } else if (idx < 8192 + 12288) {
        int j = idx - 8192;
        int n = j >> 6, k = j & 63;
        Wallt[j] = f2bs(ldin(Wsrc, (size_t)k * 192 + n, f32));
    } else if (idx < 8192 + 12288 + 8192) {
        int j = idx - 20480;
        int n = j >> 7, k = j & 127;
        Wft[j] = f2bs(ldin(Wf, (size_t)k * 64 + n, f32));
    } else if (idx < 8192 + 12288 + 8192 + 1024) {
        int j = idx - 28672;
        int n = j >> 6, k = j & 63;
        float v = 0.f;
        if (n < 3) {
            for (int c = 0; c < 64; ++c)
                v += ldin(Wsrc, (size_t)k * 192 + n * 64 + c, f32) * ldin(att_src, n * 64 + c, f32);
        } else if (n < 6) {
            for (int c = 0; c < 64; ++c)
                v += ldin(Wdst, (size_t)k * 192 + (n - 3) * 64 + c, f32) * ldin(att_dst, (n - 3) * 64 + c, f32);
        }
        Wat[j] = f2bs(v);
    }
}

// ---------- K1 (R9-proven structure): 256 threads, wave w owns col tile w, syncthreads between stages
__global__ __launch_bounds__(256) void k1_kernel(const void* __restrict__ X,
                                                 const short* __restrict__ W1t,
                                                 const short* __restrict__ Wallt,
                                                 const short* __restrict__ Wat,
                                                 const void* __restrict__ b1,
                                                 const int* __restrict__ flagp,
                                                 bf16* __restrict__ h_bf,
                                                 unsigned* __restrict__ x8,
                                                 float* __restrict__ a_src4,
                                                 float* __restrict__ a_dst4) {
    const int f32 = *flagp;
    __shared__ short hs[64 * 72];            // h tile bf16, stride 72 (2-way max: free)
    const int tid  = threadIdx.x;
    const int w    = tid >> 6;
    const int lane = tid & 63;
    const int lm   = lane & 15;
    const int q    = lane >> 4;
    const int row0 = blockIdx.x * 64;

    const float bias = ldin(b1, w * 16 + lm, f32);
    for (int mt = 0; mt < 4; ++mt) {
        f32x4 acc = {0.f, 0.f, 0.f, 0.f};
        #pragma unroll
        for (int kc = 0; kc < 4; ++kc) {
            bf16x8 a = ld8(X, (size_t)(row0 + mt * 16 + lm) * 128 + kc * 32 + q * 8, f32);
            bf16x8 b = *((const bf16x8*)(W1t + (size_t)(w * 16 + lm) * 128 + kc * 32 + q * 8));
            acc = __builtin_amdgcn_mfma_f32_16x16x32_bf16(a, b, acc, 0, 0, 0);
        }
        #pragma unroll
        for (int r = 0; r < 4; ++r) {
            int row = mt * 16 + q * 4 + r;
            float v = leaky(acc[r] + bias, 0.01f);
            short hv = f2bs(v);
            hs[row * 72 + w * 16 + lm] = hv;
            h_bf[(size_t)(row0 + row) * 64 + w * 16 + lm] = __ushort_as_bfloat16((unsigned short)hv);
        }
    }
    __syncthreads();

    for (int mt = 0; mt < 4; ++mt) {
        bf16x8 a0 = *((const bf16x8*)(hs + (mt * 16 + lm) * 72 + q * 8));
        bf16x8 a1 = *((const bf16x8*)(hs + (mt * 16 + lm) * 72 + 32 + q * 8));
        f32x4 acc[3];
        #pragma unroll
        for (int hh = 0; hh < 3; ++hh) {
            acc[hh] = (f32x4){0.f, 0.f, 0.f, 0.f};
            bf16x8 b0 = *((const bf16x8*)(Wallt + (size_t)(hh * 64 + w * 16 + lm) * 64 + q * 8));
            bf16x8 b1v = *((const bf16x8*)(Wallt + (size_t)(hh * 64 + w * 16 + lm) * 64 + 32 + q * 8));
            acc[hh] = __builtin_amdgcn_mfma_f32_16x16x32_bf16(a0, b0, acc[hh], 0, 0, 0);
            acc[hh] = __builtin_amdgcn_mfma_f32_16x16x32_bf16(a1, b1v, acc[hh], 0, 0, 0);
        }
        #pragma unroll
        for (int r = 0; r < 4; ++r) {
            int row = row0 + mt * 16 + q * 4 + r;
            unsigned p = (unsigned)__builtin_amdgcn_cvt_pk_fp8_f32(acc[0][r], acc[1][r], 0, false);
            p = (unsigned)__builtin_amdgcn_cvt_pk_fp8_f32(acc[2][r], 0.f, (int)p, true);
            x8[(size_t)row * 64 + w * 16 + lm] = p;
        }
        if (w == mt) {
            f32x4 acca = {0.f, 0.f, 0.f, 0.f};
            bf16x8 b0 = *((const bf16x8*)(Wat + (size_t)lm * 64 + q * 8));
            bf16x8 b1v = *((const bf16x8*)(Wat + (size_t)lm * 64 + 32 + q * 8));
            acca = __builtin_amdgcn_mfma_f32_16x16x32_bf16(a0, b0, acca, 0, 0, 0);
            acca = __builtin_amdgcn_mfma_f32_16x16x32_bf16(a1, b1v, acca, 0, 0, 0);
            if (lm < 6) {
                #pragma unroll
                for (int r = 0; r < 4; ++r) {
                    int row = row0 + mt * 16 + q * 4 + r;
                    if (lm < 3) a_src4[(size_t)row * 4 + lm] = acca[r];
                    else        a_dst4[(size_t)row * 4 + (lm - 3)] = acca[r];
                }
            }
        }
    }
}

// ---------- edge aggregation: wave per dst node; fused denom; LDS broadcast; fp8 HW cvt; unroll 8
__global__ __launch_bounds__(256) void edge_kernel(const unsigned short* __restrict__ bucket,
                                                   const int* __restrict__ cursor,
                                                   const float* __restrict__ a_src4,
                                                   const float* __restrict__ a_dst4,
                                                   const unsigned* __restrict__ x8,
                                                   const void* __restrict__ gat_bias,
                                                   const int* __restrict__ flagp,
                                                   float4* __restrict__ dstinfo,
                                                   bf16* __restrict__ out_agg) {
    const int f32 = *flagp;
    const int lane = threadIdx.x & 63;
    const int w = threadIdx.x >> 6;
    const int n = blockIdx.x * 4 + w;
    const int dg = min(cursor[n], CAP);
    const float4 ad = ((const float4*)a_dst4)[n];
    __shared__ float4 buf[4][64];
    float den0 = 0.f, den1 = 0.f, den2 = 0.f;
    float acc0 = 0.f, acc1 = 0.f, acc2 = 0.f;
    for (int c0 = 0; c0 < dg; c0 += 64) {
        int cnt = min(64, dg - c0);
        if (lane < cnt) {
            int s = bucket[(size_t)n * CAP + c0 + lane];
            const float4 as = ((const float4*)a_src4)[s];
            float e0 = __expf(leaky(as.x + ad.x, 0.2f));
            float e1 = __expf(leaky(as.y + ad.y, 0.2f));
            float e2 = __expf(leaky(as.z + ad.z, 0.2f));
            buf[w][lane] = make_float4(e0, e1, e2, __int_as_float(s));
        }
        asm volatile("s_waitcnt lgkmcnt(0)" ::: "memory");
        int j = 0;
        for (; j + 8 <= cnt; j += 8) {
            float4 r[8]; int xv[8];
            #pragma unroll
            for (int u = 0; u < 8; ++u) r[u] = buf[w][j + u];
            #pragma unroll
            for (int u = 0; u < 8; ++u)
                xv[u] = (int)x8[(size_t)__float_as_int(r[u].w) * 64 + lane];
            #pragma unroll
            for (int u = 0; u < 8; ++u) {
                f32x2 p = __builtin_amdgcn_cvt_pk_f32_fp8(xv[u], false);
                acc0 += r[u].x * p[0];
                acc1 += r[u].y * p[1];
                acc2 += r[u].z * __builtin_amdgcn_cvt_f32_fp8(xv[u], 2);
                den0 += r[u].x; den1 += r[u].y; den2 += r[u].z;
            }
        }
        for (; j < cnt; ++j) {
            float4 r = buf[w][j];
            int xv = (int)x8[(size_t)__float_as_int(r.w) * 64 + lane];
            f32x2 p = __builtin_amdgcn_cvt_pk_f32_fp8(xv, false);
            acc0 += r.x * p[0];
            acc1 += r.y * p[1];
            acc2 += r.z * __builtin_amdgcn_cvt_f32_fp8(xv, 2);
            den0 += r.x; den1 += r.y; den2 += r.z;
        }
    }
    float inv0 = den0 > 0.f ? 1.f / den0 : 0.f;
    float inv1 = den1 > 0.f ? 1.f / den1 : 0.f;
    float inv2 = den2 > 0.f ? 1.f / den2 : 0.f;
    float outv = (acc0 * inv0 + acc1 * inv1 + acc2 * inv2) * (1.f / 3.f) + ldin(gat_bias, lane, f32);
    out_agg[(size_t)n * DH + lane] = f2b(outv);
    if (lane == 0) {
        dstinfo[(size_t)n * 2 + 0] = make_float4(ad.x, ad.y, ad.z, 0.f);
        dstinfo[(size_t)n * 2 + 1] = make_float4(inv0, inv1, inv2, 0.f);
    }
}

// ---------- fused attn (edge-order, blocks 0..3199) + g3 MFMA (blocks 3200..3999)
__global__ __launch_bounds__(256) void attn_g3_kernel(const int* __restrict__ src,
                                                      const int* __restrict__ dst,
                                                      const float* __restrict__ a_src4,
                                                      const float4* __restrict__ dstinfo,
                                                      const bf16* __restrict__ h_bf,
                                                      const bf16* __restrict__ out_agg,
                                                      const short* __restrict__ Wft,
                                                      const void* __restrict__ bfv,
                                                      const int* __restrict__ flagp,
                                                      bf16* __restrict__ y_bf,
                                                      void* __restrict__ d_out) {
    const int f32 = *flagp;
    __shared__ short cs[64 * 136];           // used by g3 branch only
    if (blockIdx.x < N_EDGES / 256) {
        int e = blockIdx.x * 256 + threadIdx.x;
        int s = src[e], d = dst[e];
        const float4 as = ((const float4*)a_src4)[s];
        const float4 ad = dstinfo[(size_t)d * 2 + 0];
        const float4 cv = dstinfo[(size_t)d * 2 + 1];
        float a0 = __expf(leaky(as.x + ad.x, 0.2f)) * cv.x;
        float a1 = __expf(leaky(as.y + ad.y, 0.2f)) * cv.y;
        float a2 = __expf(leaky(as.z + ad.z, 0.2f)) * cv.z;
        size_t o = (size_t)N_GRAPHS * DIM_OUT + (size_t)e * 3;
        if (f32) {
            float* p = (float*)d_out;
            p[o] = a0; p[o + 1] = a1; p[o + 2] = a2;
        } else {
            bf16* p = (bf16*)d_out;
            p[o] = f2b(a0); p[o + 1] = f2b(a1); p[o + 2] = f2b(a2);
        }
        return;
    }
    const int bid  = blockIdx.x - N_EDGES / 256;
    const int tid  = threadIdx.x;
    const int w    = tid >> 6;
    const int lane = tid & 63;
    const int lm   = lane & 15;
    const int q    = lane >> 4;
    const int row0 = bid * 64;
    for (int idx = tid; idx < 64 * 64; idx += 256) {
        int r = idx >> 6, k = idx & 63;
        cs[r * 136 + k] = f2bs(leaky(b2f(h_bf[(size_t)(row0 + r) * 64 + k]), 0.01f));
    }
    for (int idx = tid; idx < 64 * 64; idx += 256) {
        int r = idx >> 6, k = idx & 63;
        cs[r * 136 + 64 + k] = f2bs(leaky(b2f(out_agg[(size_t)(row0 + r) * 64 + k]), 0.01f));
    }
    __syncthreads();
    const float bias = ldin(bfv, w * 16 + lm, f32);
    for (int mt = 0; mt < 4; ++mt) {
        f32x4 acc = {0.f, 0.f, 0.f, 0.f};
        #pragma unroll
        for (int kc = 0; kc < 4; ++kc) {
            bf16x8 a = *((const bf16x8*)(cs + (mt * 16 + lm) * 136 + kc * 32 + q * 8));
            bf16x8 b = *((const bf16x8*)(Wft + (size_t)(w * 16 + lm) * 128 + kc * 32 + q * 8));
            acc = __builtin_amdgcn_mfma_f32_16x16x32_bf16(a, b, acc, 0, 0, 0);
        }
        #pragma unroll
        for (int r = 0; r < 4; ++r) {
            int row = row0 + mt * 16 + q * 4 + r;
            y_bf[(size_t)row * 64 + w * 16 + lm] = f2b(acc[r] + bias);
        }
    }
}

// ---------- graph mean-pool: 1024 threads per graph
__global__ __launch_bounds__(1024) void pool_kernel(const bf16* __restrict__ y_bf,
                                                    const int* __restrict__ ptr,
                                                    const int* __restrict__ flagp,
                                                    void* __restrict__ d_out) {
    __shared__ float part[16][64];
    const int f32 = *flagp;
    const int g = blockIdx.x;
    const int w = threadIdx.x >> 6, lane = threadIdx.x & 63;
    const int lo = ptr[g], hi = ptr[g + 1];
    const int cnt = hi - lo;
    float s = 0.f;
    for (int i = lo + w; i < hi; i += 16) s += b2f(y_bf[(size_t)i * DIM_OUT + lane]);
    part[w][lane] = s;
    __syncthreads();
    if (threadIdx.x < 64) {
        float t = 0.f;
        #pragma unroll
        for (int k = 0; k < 16; ++k) t += part[k][threadIdx.x];
        float v = t / (float)cnt;
        if (f32) ((float*)d_out)[g * DIM_OUT + threadIdx.x] = v;
        else     ((bf16*)d_out)[g * DIM_OUT + threadIdx.x]  = f2b(v);
    }
}

extern "C" void kernel_launch(void* const* d_in, const int* in_sizes, int n_in,
                              void* d_out, int out_size, void* d_ws, size_t ws_size,
                              hipStream_t stream) {
    const void* X        = d_in[0];
    const void* W1       = d_in[1];
    const void* b1       = d_in[2];
    const void* Wsrc     = d_in[3];
    const void* Wdst     = d_in[4];
    const void* att_src  = d_in[5];
    const void* att_dst  = d_in[6];
    const void* gat_bias = d_in[7];
    const void* Wf       = d_in[8];
    const void* bfv      = d_in[9];
    const int*  ei       = (const int*)d_in[10];
    const int*  ptr      = (const int*)d_in[11];
    const int*  src  = ei;
    const int*  dstp = ei + N_EDGES;

    char* ws = (char*)d_ws;
    size_t off_b = 0;
    auto alloc = [&](size_t bytes) -> char* {
        char* p = ws + off_b;
        off_b += (bytes + 255) & ~(size_t)255;
        return p;
    };
    int*     flag    = (int*)    alloc(256);
    short*   W1t     = (short*)  alloc(8192 * 2);
    short*   Wallt   = (short*)  alloc(12288 * 2);
    short*   Wft     = (short*)  alloc(8192 * 2);
    short*   Wat     = (short*)  alloc(1024 * 2);
    bf16*    h_bf    = (bf16*)   alloc((size_t)N_NODES * 64 * 2);
    unsigned* x8     = (unsigned*)alloc((size_t)N_NODES * 64 * 4);  // fp8x3 packed; aliased by y_bf
    float*   a_src4  = (float*)  alloc((size_t)N_NODES * 16);
    float*   a_dst4  = (float*)  alloc((size_t)N_NODES * 16);
    float4*  dstinfo = (float4*) alloc((size_t)N_NODES * 2 * 16);
    bf16*    out_agg = (bf16*)   alloc((size_t)N_NODES * 64 * 2);
    int*     cursor  = (int*)    alloc((size_t)N_NODES * 4);
    unsigned short* bucket = (unsigned short*)alloc((size_t)N_NODES * CAP * 2);
    bf16*    y_bf    = (bf16*)   x8;           // alias: x8 dead before g3
    if (off_b > ws_size) return;

    hipLaunchKernelGGL(detect_kernel, dim3(1), dim3(256), 0, stream,
                       (const unsigned short*)X, flag);
    hipMemsetAsync(cursor, 0, (size_t)N_NODES * 4, stream);
    hipLaunchKernelGGL(scatter_prep_kernel,
                       dim3(NPART * (N_EDGES / 2048) + 116), dim3(256), 0, stream,
                       src, dstp, cursor, bucket,
                       W1, Wsrc, Wdst, Wf, att_src, att_dst, flag, W1t, Wallt, Wft, Wat);
    hipLaunchKernelGGL(k1_kernel, dim3(N_NODES / 64), dim3(256), 0, stream,
                       X, W1t, Wallt, Wat, b1, flag, h_bf, x8, a_src4, a_dst4);
    hipLaunchKernelGGL(edge_kernel, dim3(N_NODES / 4), dim3(256), 0, stream,
                       bucket, cursor, a_src4, a_dst4, x8, gat_bias, flag, dstinfo, out_agg);
    hipLaunchKernelGGL(attn_g3_kernel, dim3(N_EDGES / 256 + N_NODES / 64), dim3(256), 0, stream,
                       src, dstp, a_src4, dstinfo, h_bf, out_agg, Wft, bfv, flag, y_bf, d_out);
    hipLaunchKernelGGL(pool_kernel, dim3(N_GRAPHS), dim3(1024), 0, stream, y_bf, ptr, flag, d_out);
}